// Round 1
// baseline (3399.487 us; speedup 1.0000x reference)
//
#include <hip/hip_runtime.h>
#include <math.h>

#define BS 16
#define S 512
#define D 1024
#define H 16
#define DK 64
#define HALF 8

constexpr float R_ = 1.0f;
constexpr float GAMMA = 0.1f;
constexpr float EPS = 1e-6f;
constexpr float INV = 0.125f; // 1/sqrt(DK)

// ---------------------------------------------------------------------------
// GEMM: C[M,N] = A[M,K] * W[N,K]^T + bias[N]
// A row-major [M][K], W row-major [N][K] (both K-contiguous => NT gemm).
// HEAD_LAYOUT: write C as [b][h][s][dk] (b=m>>9, s=m&511, h=n>>6, dk=n&63)
// else plain row-major [M][N].
// M=8192, N=1024, K=1024. Tile 64x64, BK=16, 256 threads, 4x4 micro-tile.
// ---------------------------------------------------------------------------
template <bool HEAD_LAYOUT>
__global__ __launch_bounds__(256) void gemm_bias_nt(
    const float* __restrict__ A, const float* __restrict__ W,
    const float* __restrict__ bias, float* __restrict__ C) {
  const int K = 1024, N = 1024;
  __shared__ float As[16][68]; // stride 68 floats = 272B (16B multiple)
  __shared__ float Bs[16][68];

  const int tid = threadIdx.x;
  const int bn = blockIdx.x; // N/64 = 16
  const int bm = blockIdx.y; // M/64 = 128
  const int tx = tid & 15, ty = tid >> 4;
  const int lm = tid >> 2;        // 0..63
  const int lk = (tid & 3) * 4;   // 0,4,8,12

  const float* Abase = A + (size_t)(bm * 64 + lm) * K + lk;
  const float* Wbase = W + (size_t)(bn * 64 + lm) * K + lk;

  float acc[4][4] = {};

  for (int k0 = 0; k0 < K; k0 += 16) {
    float4 av = *(const float4*)(Abase + k0);
    float4 bv = *(const float4*)(Wbase + k0);
    As[lk + 0][lm] = av.x; As[lk + 1][lm] = av.y;
    As[lk + 2][lm] = av.z; As[lk + 3][lm] = av.w;
    Bs[lk + 0][lm] = bv.x; Bs[lk + 1][lm] = bv.y;
    Bs[lk + 2][lm] = bv.z; Bs[lk + 3][lm] = bv.w;
    __syncthreads();
#pragma unroll
    for (int kk = 0; kk < 16; kk++) {
      float a[4], b[4];
#pragma unroll
      for (int i = 0; i < 4; i++) a[i] = As[kk][ty * 4 + i];
#pragma unroll
      for (int j = 0; j < 4; j++) b[j] = Bs[kk][tx * 4 + j];
#pragma unroll
      for (int i = 0; i < 4; i++)
#pragma unroll
        for (int j = 0; j < 4; j++) acc[i][j] += a[i] * b[j];
    }
    __syncthreads();
  }

#pragma unroll
  for (int i = 0; i < 4; i++) {
    const int m = bm * 64 + ty * 4 + i;
#pragma unroll
    for (int j = 0; j < 4; j++) {
      const int n = bn * 64 + tx * 4 + j;
      const float c = acc[i][j] + bias[n];
      if (HEAD_LAYOUT) {
        const int bb = m >> 9, ss = m & 511, hh = n >> 6, dd = n & 63;
        C[(((size_t)bb * H + hh) * S + ss) * DK + dd] = c;
      } else {
        C[(size_t)m * N + n] = c;
      }
    }
  }
}

// ---------------------------------------------------------------------------
// psi transform (in place) for heads HALF..H-1 of X ([B][H][S][DK] f32):
//   y = sigmoid(x[63]);  x[0..62] *= y*R;  x[63] = y*R;  Xn = sum(x[0..62]^2)
// one 64-thread block per (s, hh, b)
// ---------------------------------------------------------------------------
__global__ __launch_bounds__(64) void psi_kernel(float* __restrict__ X,
                                                 float* __restrict__ Xn) {
  const int s = blockIdx.x, hh = blockIdx.y, b = blockIdx.z;
  const int h = HALF + hh;
  float* row = X + (((size_t)b * H + h) * S + s) * DK;
  const int t = threadIdx.x;
  float v = row[t];
  const float last = __shfl(v, 63, 64);
  const float y = 1.0f / (1.0f + expf(-last)); // sigmoid, R=1
  const float xv = (t < 63) ? v * y * R_ : y * R_;
  row[t] = xv;
  float sq = (t < 63) ? xv * xv : 0.0f;
#pragma unroll
  for (int off = 32; off; off >>= 1) sq += __shfl_xor(sq, off, 64);
  if (t == 0) Xn[((size_t)b * HALF + hh) * S + s] = sq;
}

// ---------------------------------------------------------------------------
// Attention: one 256-thread block per (qi, h, b).
// Heads 0..7: standard  s = q.k*INV + alibi
// Heads 8..15: penumbral on psi-transformed q,k (63 dims; elem 63 = y)
// Strict causal mask (k < qi); row 0 output = 0.
// O written as [b][s][h*DK+dk] (row-major [8192][1024]) for the out-proj GEMM.
// ---------------------------------------------------------------------------
__global__ __launch_bounds__(256) void attn_kernel(
    const float* __restrict__ Q, const float* __restrict__ K,
    const float* __restrict__ V, const float* __restrict__ Qn,
    const float* __restrict__ Kn, const float* __restrict__ alibi,
    float* __restrict__ O) {
  const int qi = blockIdx.x, h = blockIdx.y, b = blockIdx.z;
  const int tid = threadIdx.x;
  const size_t headoff = ((size_t)b * H + h) * S * DK;
  float* orow = O + ((size_t)b * S + qi) * D + h * DK;

  if (qi == 0) {
    if (tid < DK) orow[tid] = 0.0f;
    return;
  }

  __shared__ __align__(16) float sQ[DK];
  __shared__ float sc[S];
  __shared__ float red[8];
  __shared__ float opart[4][DK];

  if (tid < DK) sQ[tid] = Q[headoff + (size_t)qi * DK + tid];
  __syncthreads();

  const bool pen = (h >= HALF);
  float qy = 0.f, qn = 0.f, qy2 = 0.f, xqy = 0.f;
  if (pen) {
    qy = sQ[63];
    qn = Qn[((size_t)b * HALF + (h - HALF)) * S + qi];
    qy2 = qy * qy;
    xqy = sqrtf(R_ * R_ - qy2 + EPS);
  }
  const float* Kh = K + headoff;
  const float* Knh = Kn + ((size_t)b * HALF + (h - HALF)) * S;
  const float* al = alibi + ((size_t)h * S + qi) * S;

  for (int k = tid; k < S; k += 256) {
    float scv = -1e32f;
    if (k < qi) {
      const float4* k4 = (const float4*)(Kh + (size_t)k * DK);
      const float4* q4 = (const float4*)sQ;
      if (!pen) {
        float acc = 0.f;
#pragma unroll
        for (int c = 0; c < 16; c++) {
          float4 kv = k4[c], qv = q4[c];
          acc += qv.x * kv.x + qv.y * kv.y + qv.z * kv.z + qv.w * kv.w;
        }
        scv = acc * INV + al[k];
      } else {
        float dot = 0.f, ky = 0.f;
#pragma unroll
        for (int c = 0; c < 16; c++) {
          float4 kv = k4[c], qv = q4[c];
          if (c < 15) {
            dot += qv.x * kv.x + qv.y * kv.y + qv.z * kv.z + qv.w * kv.w;
          } else {
            dot += qv.x * kv.x + qv.y * kv.y + qv.z * kv.z;
            ky = kv.w;
          }
        }
        const float kn = Knh[k];
        const float ky2 = ky * ky;
        const float d2 = qn + kn - 2.0f * dot;
        const float pd = sqrtf(fmaxf(d2, 0.0f) + 1e-12f);
        const float xky = sqrtf(R_ * R_ - ky2 + EPS);
        const float tmp = (xqy + xky - pd) * 0.5f;
        const float lca = fmaxf(fmaxf(qy2, ky2), R_ * R_ - tmp * tmp);
        const float num = (pd * pd + ky2 - qy2) / (2.0f * pd + EPS);
        const float lca_out = num * num + qy2;
        const bool exists =
            (pd <= xqy) || ((pd - xqy) * (pd - xqy) + ky2 <= R_ * R_);
        const float val = exists ? lca : lca_out;
        scv = (-GAMMA * val) * INV + al[k];
      }
    }
    sc[k] = scv;
  }
  __syncthreads();

  // block max
  float m = -1e32f;
  for (int k = tid; k < S; k += 256) m = fmaxf(m, sc[k]);
#pragma unroll
  for (int off = 32; off; off >>= 1) m = fmaxf(m, __shfl_xor(m, off, 64));
  if ((tid & 63) == 0) red[tid >> 6] = m;
  __syncthreads();
  m = fmaxf(fmaxf(red[0], red[1]), fmaxf(red[2], red[3]));

  // exp + block sum
  float lsum = 0.f;
  for (int k = tid; k < S; k += 256) {
    const float p = __expf(sc[k] - m);
    sc[k] = p;
    lsum += p;
  }
#pragma unroll
  for (int off = 32; off; off >>= 1) lsum += __shfl_xor(lsum, off, 64);
  if ((tid & 63) == 0) red[4 + (tid >> 6)] = lsum;
  __syncthreads();
  const float rinv = 1.0f / (red[4] + red[5] + red[6] + red[7]);

  // PV: 4 groups of 64 lanes; lane owns one dk, group strides k
  const int g = tid >> 6, dk = tid & 63;
  const float* Vh = V + headoff;
  float acc = 0.f;
  for (int k = g; k < qi; k += 4) acc += sc[k] * Vh[(size_t)k * DK + dk];
  opart[g][dk] = acc;
  __syncthreads();
  if (tid < DK) {
    orow[tid] =
        (opart[0][tid] + opart[1][tid] + opart[2][tid] + opart[3][tid]) * rinv;
  }
}

// ---------------------------------------------------------------------------
extern "C" void kernel_launch(void* const* d_in, const int* in_sizes, int n_in,
                              void* d_out, int out_size, void* d_ws,
                              size_t ws_size, hipStream_t stream) {
  (void)in_sizes; (void)n_in; (void)out_size; (void)ws_size;
  const float* x  = (const float*)d_in[0];
  const float* Wq = (const float*)d_in[1];
  const float* bq = (const float*)d_in[2];
  const float* Wk = (const float*)d_in[3];
  const float* bk = (const float*)d_in[4];
  const float* Wv = (const float*)d_in[5];
  const float* bv = (const float*)d_in[6];
  const float* Wo = (const float*)d_in[7];
  const float* bo = (const float*)d_in[8];
  const float* alibi = (const float*)d_in[9];
  float* out = (float*)d_out;

  const size_t NQKV = (size_t)BS * H * S * DK; // 8388608
  float* Q  = (float*)d_ws;
  float* Kb = Q + NQKV;
  float* Vb = Kb + NQKV;
  float* O  = Vb + NQKV;
  float* Qn = O + (size_t)BS * S * D;
  float* Kn = Qn + (size_t)BS * HALF * S;

  dim3 gg(16, 128); // N/64, M/64
  gemm_bias_nt<true><<<gg, 256, 0, stream>>>(x, Wq, bq, Q);
  gemm_bias_nt<true><<<gg, 256, 0, stream>>>(x, Wk, bk, Kb);
  gemm_bias_nt<true><<<gg, 256, 0, stream>>>(x, Wv, bv, Vb);
  psi_kernel<<<dim3(S, HALF, BS), 64, 0, stream>>>(Q, Qn);
  psi_kernel<<<dim3(S, HALF, BS), 64, 0, stream>>>(Kb, Kn);
  attn_kernel<<<dim3(S, H, BS), 256, 0, stream>>>(Q, Kb, Vb, Qn, Kn, alibi, O);
  gemm_bias_nt<false><<<gg, 256, 0, stream>>>(O, Wo, bo, out);
}

// Round 2
// 1103.804 us; speedup vs baseline: 3.0798x; 3.0798x over previous
//
#include <hip/hip_runtime.h>
#include <math.h>

#define BS 16
#define S 512
#define D 1024
#define H 16
#define DK 64
#define HALF 8

typedef __attribute__((ext_vector_type(8))) short short8v;
typedef __attribute__((ext_vector_type(4))) float f32x4;
typedef unsigned short ushort_t;

__device__ __forceinline__ ushort_t f2bf(float f) {
  union { float f; unsigned u; } v; v.f = f;
  unsigned r = v.u + 0x7fffu + ((v.u >> 16) & 1u);
  return (ushort_t)(r >> 16);
}
__device__ __forceinline__ unsigned packbf(float a, float b) {
  return (unsigned)f2bf(a) | ((unsigned)f2bf(b) << 16);
}

// ---------------------------------------------------------------------------
// GEMM: C[M,N] = A[M,K] * W[N,K]^T + bias[N]  (f32, unchanged from R1)
// ---------------------------------------------------------------------------
template <bool HEAD_LAYOUT>
__global__ __launch_bounds__(256) void gemm_bias_nt(
    const float* __restrict__ A, const float* __restrict__ W,
    const float* __restrict__ bias, float* __restrict__ C) {
  const int K = 1024, N = 1024;
  __shared__ float As[16][68];
  __shared__ float Bs[16][68];

  const int tid = threadIdx.x;
  const int bn = blockIdx.x;
  const int bm = blockIdx.y;
  const int tx = tid & 15, ty = tid >> 4;
  const int lm = tid >> 2;
  const int lk = (tid & 3) * 4;

  const float* Abase = A + (size_t)(bm * 64 + lm) * K + lk;
  const float* Wbase = W + (size_t)(bn * 64 + lm) * K + lk;

  float acc[4][4] = {};

  for (int k0 = 0; k0 < K; k0 += 16) {
    float4 av = *(const float4*)(Abase + k0);
    float4 bv = *(const float4*)(Wbase + k0);
    As[lk + 0][lm] = av.x; As[lk + 1][lm] = av.y;
    As[lk + 2][lm] = av.z; As[lk + 3][lm] = av.w;
    Bs[lk + 0][lm] = bv.x; Bs[lk + 1][lm] = bv.y;
    Bs[lk + 2][lm] = bv.z; Bs[lk + 3][lm] = bv.w;
    __syncthreads();
#pragma unroll
    for (int kk = 0; kk < 16; kk++) {
      float a[4], b[4];
#pragma unroll
      for (int i = 0; i < 4; i++) a[i] = As[kk][ty * 4 + i];
#pragma unroll
      for (int j = 0; j < 4; j++) b[j] = Bs[kk][tx * 4 + j];
#pragma unroll
      for (int i = 0; i < 4; i++)
#pragma unroll
        for (int j = 0; j < 4; j++) acc[i][j] += a[i] * b[j];
    }
    __syncthreads();
  }

#pragma unroll
  for (int i = 0; i < 4; i++) {
    const int m = bm * 64 + ty * 4 + i;
#pragma unroll
    for (int j = 0; j < 4; j++) {
      const int n = bn * 64 + tx * 4 + j;
      const float c = acc[i][j] + bias[n];
      if (HEAD_LAYOUT) {
        const int bb = m >> 9, ss = m & 511, hh = n >> 6, dd = n & 63;
        C[(((size_t)bb * H + hh) * S + ss) * DK + dd] = c;
      } else {
        C[(size_t)m * N + n] = c;
      }
    }
  }
}

// ---------------------------------------------------------------------------
// psi transform (in place) for heads HALF..H-1 (unchanged from R1)
// ---------------------------------------------------------------------------
__global__ __launch_bounds__(64) void psi_kernel(float* __restrict__ X,
                                                 float* __restrict__ Xn) {
  const int s = blockIdx.x, hh = blockIdx.y, b = blockIdx.z;
  const int h = HALF + hh;
  float* row = X + (((size_t)b * H + h) * S + s) * DK;
  const int t = threadIdx.x;
  float v = row[t];
  const float last = __shfl(v, 63, 64);
  const float y = 1.0f / (1.0f + expf(-last));
  const float xv = (t < 63) ? v * y : y;
  row[t] = xv;
  float sq = (t < 63) ? xv * xv : 0.0f;
#pragma unroll
  for (int off = 32; off; off >>= 1) sq += __shfl_xor(sq, off, 64);
  if (t == 0) Xn[((size_t)b * HALF + hh) * S + s] = sq;
}

// ---------------------------------------------------------------------------
// pack V -> bf16 transposed [dk][s], IN PLACE at the front of each f32 slab.
// One block per (b,h). All reads complete before any write (barrier).
// ---------------------------------------------------------------------------
__global__ __launch_bounds__(256) void pack_vt(float* __restrict__ V) {
  const int bh = blockIdx.x;
  float* slab = V + (size_t)bh * (S * DK);
  __shared__ ushort_t sT[DK][S + 8];
  const int tid = threadIdx.x;
  for (int i = tid; i < (S * DK) / 4; i += 256) {
    const int s = i >> 4, dk4 = (i & 15) * 4;
    float4 v = *(const float4*)(slab + (size_t)s * DK + dk4);
    sT[dk4 + 0][s] = f2bf(v.x);
    sT[dk4 + 1][s] = f2bf(v.y);
    sT[dk4 + 2][s] = f2bf(v.z);
    sT[dk4 + 3][s] = f2bf(v.w);
  }
  __syncthreads();
  ushort_t* out = (ushort_t*)slab;
  for (int i = tid; i < (S * DK) / 8; i += 256) {
    const int dk = i >> 6, c8 = (i & 63) * 8;
    union { short8v v; ushort_t u[8]; } t;
#pragma unroll
    for (int j = 0; j < 8; j++) t.u[j] = sT[dk][c8 + j];
    *(short8v*)(out + (size_t)dk * S + c8) = t.v;
  }
}

// ---------------------------------------------------------------------------
// Flash attention, bf16 MFMA 16x16x32.
// Block = (qb, h, b): 64 q-rows, 4 waves x 16 q-rows. Causal k-tiles of 64.
// Swapped QK^T (lane owns q-col) -> in-register online softmax -> shfl-built
// P^T fragments -> swapped PV -> float4 epilogue.
// ---------------------------------------------------------------------------
__global__ __launch_bounds__(256) void attn_mfma(
    const float* __restrict__ Qf, const float* __restrict__ Kf,
    const float* __restrict__ Vf, const float* __restrict__ Qn,
    const float* __restrict__ Kn, float* __restrict__ O) {
  const int qb = blockIdx.x, h = blockIdx.y, b = blockIdx.z;
  const int tid = threadIdx.x, lane = tid & 63, wid = tid >> 6;
  const int lq = lane & 15, g = lane >> 4;
  const int qg = qb * 64 + wid * 16 + lq;
  const bool pen = (h >= HALF);
  const float slope = -exp2f(-0.5f * (float)(h + 1));
  const size_t hoff = ((size_t)b * H + h) * S * DK;
  const ushort_t* Vt = (const ushort_t*)(Vf + hoff);  // packed [dk][s] bf16

  __shared__ __align__(16) char sK[64 * 128];
  __shared__ __align__(16) char sV[64 * 128];
  __shared__ float sKn[64];
  __shared__ float sKy[64];

  // Q fragments (B-operand: col = lq = q, k-dim = dk = c*32 + g*8 + j)
  const float* qrow = Qf + hoff + (size_t)qg * DK;
  short8v qfrag[2];
#pragma unroll
  for (int c = 0; c < 2; c++) {
    float4 f0 = *(const float4*)(qrow + c * 32 + g * 8);
    float4 f1 = *(const float4*)(qrow + c * 32 + g * 8 + 4);
    short8v q;
    q[0] = (short)f2bf(f0.x); q[1] = (short)f2bf(f0.y);
    q[2] = (short)f2bf(f0.z); q[3] = (short)f2bf(f0.w);
    q[4] = (short)f2bf(f1.x); q[5] = (short)f2bf(f1.y);
    q[6] = (short)f2bf(f1.z); q[7] = (short)f2bf(f1.w);
    qfrag[c] = q;
  }
  float qy = 0.f, qnv = 0.f, qy2 = 0.f, xqy = 0.f;
  if (pen) {
    qy = qrow[63];
    qnv = Qn[((size_t)b * HALF + (h - HALF)) * S + qg];
    qy2 = qy * qy;
    xqy = sqrtf(1.0f - qy2 + 1e-6f);
  }

  f32x4 o[4];
#pragma unroll
  for (int dt = 0; dt < 4; dt++) o[dt] = (f32x4){0.f, 0.f, 0.f, 0.f};
  float m = -1e30f, lacc = 0.f;

  const int srow = tid >> 2, squad = tid & 3;

  for (int kt = 0; kt <= qb; ++kt) {
    // ---- stage K tile (f32 -> bf16, XOR-swizzled rows) + V^T tile ----
    {
      const float* ks = Kf + hoff + (size_t)(kt * 64 + srow) * DK + squad * 16;
      float4 a0 = *(const float4*)(ks);
      float4 a1 = *(const float4*)(ks + 4);
      float4 a2 = *(const float4*)(ks + 8);
      float4 a3 = *(const float4*)(ks + 12);
      union { short8v v; ushort_t u[8]; } h0, h1;
      h0.u[0] = f2bf(a0.x); h0.u[1] = f2bf(a0.y);
      h0.u[2] = f2bf(a0.z); h0.u[3] = f2bf(a0.w);
      h0.u[4] = f2bf(a1.x); h0.u[5] = f2bf(a1.y);
      h0.u[6] = f2bf(a1.z); h0.u[7] = f2bf(a1.w);
      h1.u[0] = f2bf(a2.x); h1.u[1] = f2bf(a2.y);
      h1.u[2] = f2bf(a2.z); h1.u[3] = f2bf(a2.w);
      h1.u[4] = f2bf(a3.x); h1.u[5] = f2bf(a3.y);
      h1.u[6] = f2bf(a3.z); h1.u[7] = f2bf(a3.w);
      if (pen && squad == 3) h1.u[7] = 0;  // zero y-element so MFMA dot is 63-dim
      const int swz = (srow & 7) << 4;
      *(short8v*)(sK + srow * 128 + ((squad * 32) ^ swz)) = h0.v;
      *(short8v*)(sK + srow * 128 + ((squad * 32 + 16) ^ swz)) = h1.v;

      const ushort_t* vs = Vt + (size_t)srow * S + kt * 64 + squad * 16;
      short8v v0 = *(const short8v*)(vs);
      short8v v1 = *(const short8v*)(vs + 8);
      *(short8v*)(sV + srow * 128 + ((squad * 32) ^ swz)) = v0;
      *(short8v*)(sV + srow * 128 + ((squad * 32 + 16) ^ swz)) = v1;

      if (pen) {
        if (tid < 64)
          sKn[tid] = Kn[((size_t)b * HALF + (h - HALF)) * S + kt * 64 + tid];
        else if (tid < 128)
          sKy[tid - 64] = Kf[hoff + (size_t)(kt * 64 + tid - 64) * DK + 63];
      }
    }
    __syncthreads();

    // ---- scores: D[k][q] via swapped mfma(K, Q) ----
    float p[4][4];
    float tmax = -1e30f;
#pragma unroll
    for (int t4 = 0; t4 < 4; ++t4) {
      f32x4 acc = (f32x4){0.f, 0.f, 0.f, 0.f};
#pragma unroll
      for (int c = 0; c < 2; ++c) {
        const int row = t4 * 16 + lq;
        const short8v ka = *(const short8v*)(
            sK + row * 128 + ((c * 64 + g * 16) ^ ((row & 7) << 4)));
        acc = __builtin_amdgcn_mfma_f32_16x16x32_bf16(ka, qfrag[c], acc, 0, 0, 0);
      }
      float4 kn4, ky4;
      if (pen) {
        kn4 = *(const float4*)(sKn + t4 * 16 + g * 4);
        ky4 = *(const float4*)(sKy + t4 * 16 + g * 4);
      }
#pragma unroll
      for (int r = 0; r < 4; ++r) {
        const int kg = kt * 64 + t4 * 16 + g * 4 + r;
        float s = -1e30f;
        if (kg < qg) {
          const float dot = acc[r];
          const float ab = slope * (float)(qg - kg);
          if (!pen) {
            s = dot * 0.125f + ab;
          } else {
            const float kn = ((const float*)&kn4)[r];
            const float ky = ((const float*)&ky4)[r];
            const float ky2 = ky * ky;
            const float d2 = qnv + kn - 2.0f * dot;
            const float pd = sqrtf(fmaxf(d2, 0.0f) + 1e-12f);
            const float xky = sqrtf(1.0f - ky2 + 1e-6f);
            const float tmp = (xqy + xky - pd) * 0.5f;
            const float lca = fmaxf(fmaxf(qy2, ky2), 1.0f - tmp * tmp);
            const float num = (pd * pd + ky2 - qy2) / (2.0f * pd + 1e-6f);
            const float lout = num * num + qy2;
            const float dxy = pd - xqy;
            const bool exists = (pd <= xqy) || (dxy * dxy + ky2 <= 1.0f);
            s = -0.1f * (exists ? lca : lout) * 0.125f + ab;
          }
        }
        p[t4][r] = s;
        tmax = fmaxf(tmax, s);
      }
    }
    // row reduce across the 4-lane group (same q)
    tmax = fmaxf(tmax, __shfl_xor(tmax, 16, 64));
    tmax = fmaxf(tmax, __shfl_xor(tmax, 32, 64));
    const float mnew = fmaxf(m, tmax);
    const float fsc = __expf(m - mnew);
    float ls = 0.f;
#pragma unroll
    for (int t4 = 0; t4 < 4; ++t4)
#pragma unroll
      for (int r = 0; r < 4; ++r) {
        const float sc = p[t4][r];
        float pv = __expf(sc - mnew);
        if (sc < -1e29f) pv = 0.f;
        p[t4][r] = pv;
        ls += pv;
      }
    ls += __shfl_xor(ls, 16, 64);
    ls += __shfl_xor(ls, 32, 64);
    lacc = lacc * fsc + ls;
    m = mnew;
#pragma unroll
    for (int dt = 0; dt < 4; ++dt) o[dt] = o[dt] * fsc;

    // ---- pack P to bf16 pairs; build P^T B-frags via shfl; PV MFMAs ----
    unsigned pk0[4], pk1[4];
#pragma unroll
    for (int t4 = 0; t4 < 4; ++t4) {
      pk0[t4] = packbf(p[t4][0], p[t4][1]);
      pk1[t4] = packbf(p[t4][2], p[t4][3]);
    }
    const int s0 = lq | (((g * 2) & 3) << 4);
    const int s1 = lq | (((g * 2 + 1) & 3) << 4);
    const bool hi = (g >= 2);
#pragma unroll
    for (int c = 0; c < 2; ++c) {
      const unsigned a0 = (unsigned)__shfl((int)pk0[2 * c], s0, 64);
      const unsigned b0 = (unsigned)__shfl((int)pk0[2 * c + 1], s0, 64);
      const unsigned a1 = (unsigned)__shfl((int)pk1[2 * c], s0, 64);
      const unsigned b1 = (unsigned)__shfl((int)pk1[2 * c + 1], s0, 64);
      const unsigned a2 = (unsigned)__shfl((int)pk0[2 * c], s1, 64);
      const unsigned b2 = (unsigned)__shfl((int)pk0[2 * c + 1], s1, 64);
      const unsigned a3 = (unsigned)__shfl((int)pk1[2 * c], s1, 64);
      const unsigned b3 = (unsigned)__shfl((int)pk1[2 * c + 1], s1, 64);
      union { short8v v; unsigned u[4]; } pb;
      pb.u[0] = hi ? b0 : a0;
      pb.u[1] = hi ? b1 : a1;
      pb.u[2] = hi ? b2 : a2;
      pb.u[3] = hi ? b3 : a3;
#pragma unroll
      for (int dt = 0; dt < 4; ++dt) {
        const int vr = dt * 16 + lq;
        const short8v va = *(const short8v*)(
            sV + vr * 128 + ((c * 64 + g * 16) ^ ((vr & 7) << 4)));
        o[dt] = __builtin_amdgcn_mfma_f32_16x16x32_bf16(va, pb.v, o[dt], 0, 0, 0);
      }
    }
    __syncthreads();
  }

  const float invl = (qg == 0) ? 0.f : 1.0f / lacc;
  float* orow = O + ((size_t)b * S + qg) * D + h * DK;
#pragma unroll
  for (int dt = 0; dt < 4; ++dt) {
    float4 vv = make_float4(o[dt][0] * invl, o[dt][1] * invl,
                            o[dt][2] * invl, o[dt][3] * invl);
    *(float4*)(orow + dt * 16 + g * 4) = vv;
  }
}

// ---------------------------------------------------------------------------
extern "C" void kernel_launch(void* const* d_in, const int* in_sizes, int n_in,
                              void* d_out, int out_size, void* d_ws,
                              size_t ws_size, hipStream_t stream) {
  (void)in_sizes; (void)n_in; (void)out_size; (void)ws_size;
  const float* x  = (const float*)d_in[0];
  const float* Wq = (const float*)d_in[1];
  const float* bq = (const float*)d_in[2];
  const float* Wk = (const float*)d_in[3];
  const float* bk = (const float*)d_in[4];
  const float* Wv = (const float*)d_in[5];
  const float* bv = (const float*)d_in[6];
  const float* Wo = (const float*)d_in[7];
  const float* bo = (const float*)d_in[8];
  float* out = (float*)d_out;

  const size_t NQKV = (size_t)BS * H * S * DK;
  float* Q  = (float*)d_ws;
  float* Kb = Q + NQKV;
  float* Vb = Kb + NQKV;
  float* O  = Vb + NQKV;
  float* Qn = O + (size_t)BS * S * D;
  float* Kn = Qn + (size_t)BS * HALF * S;

  dim3 gg(16, 128);
  gemm_bias_nt<true><<<gg, 256, 0, stream>>>(x, Wq, bq, Q);
  gemm_bias_nt<true><<<gg, 256, 0, stream>>>(x, Wk, bk, Kb);
  gemm_bias_nt<true><<<gg, 256, 0, stream>>>(x, Wv, bv, Vb);
  psi_kernel<<<dim3(S, HALF, BS), 64, 0, stream>>>(Q, Qn);
  psi_kernel<<<dim3(S, HALF, BS), 64, 0, stream>>>(Kb, Kn);
  pack_vt<<<dim3(BS * H), 256, 0, stream>>>(Vb);
  attn_mfma<<<dim3(S / 64, H, BS), 256, 0, stream>>>(Q, Kb, Vb, Qn, Kn, O);
  gemm_bias_nt<false><<<gg, 256, 0, stream>>>(O, Wo, bo, out);
}

// Round 3
// 272.220 us; speedup vs baseline: 12.4880x; 4.0548x over previous
//
#include <hip/hip_runtime.h>
#include <math.h>

#define BS 16
#define S 512
#define D 1024
#define H 16
#define DK 64
#define HALF 8

typedef __attribute__((ext_vector_type(8))) short short8v;
typedef __attribute__((ext_vector_type(4))) float f32x4;
typedef unsigned short ushort_t;

__device__ __forceinline__ ushort_t f2bf(float f) {
  union { float f; unsigned u; } v; v.f = f;
  unsigned r = v.u + 0x7fffu + ((v.u >> 16) & 1u);
  return (ushort_t)(r >> 16);
}
__device__ __forceinline__ unsigned packbf(float a, float b) {
  return (unsigned)f2bf(a) | ((unsigned)f2bf(b) << 16);
}
__device__ __forceinline__ float bf2f(ushort_t u) {
  union { unsigned u; float f; } v; v.u = ((unsigned)u) << 16;
  return v.f;
}

__device__ __forceinline__ void gload16(const void* g, void* l) {
  __builtin_amdgcn_global_load_lds(
      (const __attribute__((address_space(1))) unsigned int*)g,
      (__attribute__((address_space(3))) unsigned int*)l, 16, 0, 0);
}

// ---------------------------------------------------------------------------
// f32 -> bf16 convert, 8 elems/thread
// ---------------------------------------------------------------------------
__global__ __launch_bounds__(256) void cvt_bf16(const float* __restrict__ in,
                                                ushort_t* __restrict__ out,
                                                int n8) {
  const int i = blockIdx.x * 256 + threadIdx.x;
  if (i >= n8) return;
  const float4 a = *(const float4*)(in + (size_t)i * 8);
  const float4 b = *(const float4*)(in + (size_t)i * 8 + 4);
  union { short8v v; unsigned u[4]; } t;
  t.u[0] = packbf(a.x, a.y);
  t.u[1] = packbf(a.z, a.w);
  t.u[2] = packbf(b.x, b.y);
  t.u[3] = packbf(b.z, b.w);
  *(short8v*)(out + (size_t)i * 8) = t.v;
}

// ---------------------------------------------------------------------------
// bf16 MFMA GEMM: C[M=8192,N=1024] = A[M,K=1024] * B[N,K]^T + bias
// 128x128 tile, BK=64, 4 waves (2x2), 4x4 16x16x32 frags per wave.
// global_load_lds staging with source pre-swizzle (slot ^= row&7) so
// ds_read_b128 fragment reads are 2-way (free).
// EPI 0: bf16 head layout [b][h][s][dk];  EPI 1: bf16 V^T [b][h][dk][s];
// EPI 2: f32 row-major [M][N].
// ---------------------------------------------------------------------------
template <int EPI>
__global__ __launch_bounds__(256) void gemm_mfma(
    const ushort_t* __restrict__ A, const ushort_t* __restrict__ B,
    const float* __restrict__ bias, void* __restrict__ Cout) {
  const int tid = threadIdx.x;
  const int lane = tid & 63, wid = tid >> 6;
  const int wr = wid >> 1, wc = wid & 1;
  const int lq = lane & 15, g = lane >> 4;
  const int bn = blockIdx.x;  // N/128 = 8
  const int bm = blockIdx.y;  // M/128 = 64

  __shared__ __align__(16) ushort_t sA[128 * 64];
  __shared__ __align__(16) ushort_t sB[128 * 64];

  f32x4 acc[4][4];
#pragma unroll
  for (int i = 0; i < 4; i++)
#pragma unroll
    for (int j = 0; j < 4; j++) acc[i][j] = (f32x4){0.f, 0.f, 0.f, 0.f};

  for (int k0 = 0; k0 < 1024; k0 += 64) {
#pragma unroll
    for (int is = 0; is < 4; ++is) {
      const int gi = is * 256 + tid;
      const int row = gi >> 3, slot = gi & 7;
      const int sslot = slot ^ (row & 7);
      const ushort_t* srcA =
          A + (size_t)(bm * 128 + row) * 1024 + k0 + sslot * 8;
      const ushort_t* srcB =
          B + (size_t)(bn * 128 + row) * 1024 + k0 + sslot * 8;
      gload16(srcA, &sA[(is * 256 + wid * 64) * 8]);
      gload16(srcB, &sB[(is * 256 + wid * 64) * 8]);
    }
    __syncthreads();
#pragma unroll
    for (int ks = 0; ks < 2; ++ks) {
      short8v af[4], bf[4];
#pragma unroll
      for (int i = 0; i < 4; ++i) {
        const int arow = wr * 64 + i * 16 + lq;
        af[i] = *(const short8v*)&sA[arow * 64 + (((ks * 4 + g) ^ (arow & 7)) * 8)];
        const int brow = wc * 64 + i * 16 + lq;
        bf[i] = *(const short8v*)&sB[brow * 64 + (((ks * 4 + g) ^ (brow & 7)) * 8)];
      }
#pragma unroll
      for (int i = 0; i < 4; ++i)
#pragma unroll
        for (int j = 0; j < 4; ++j)
          acc[i][j] =
              __builtin_amdgcn_mfma_f32_16x16x32_bf16(af[i], bf[j], acc[i][j], 0, 0, 0);
    }
    __syncthreads();
  }

#pragma unroll
  for (int j = 0; j < 4; ++j) {
    const int n = bn * 128 + wc * 64 + j * 16 + lq;
    const float bv = bias[n];
#pragma unroll
    for (int i = 0; i < 4; ++i) {
      const int mb = bm * 128 + wr * 64 + i * 16 + g * 4;
      if (EPI == 0) {
        ushort_t* C = (ushort_t*)Cout;
#pragma unroll
        for (int r = 0; r < 4; ++r) {
          const int m = mb + r;
          const float c = acc[i][j][r] + bv;
          C[((((size_t)(m >> 9) * H + (n >> 6)) * S + (m & 511)) * DK) +
            (n & 63)] = f2bf(c);
        }
      } else if (EPI == 1) {
        ushort_t* C = (ushort_t*)Cout;
        const int bb = mb >> 9, s0 = mb & 511;
        uint2 u;
        u.x = packbf(acc[i][j][0] + bv, acc[i][j][1] + bv);
        u.y = packbf(acc[i][j][2] + bv, acc[i][j][3] + bv);
        *(uint2*)(C + (((size_t)bb * H + (n >> 6)) * DK + (n & 63)) * S + s0) = u;
      } else {
        float* C = (float*)Cout;
#pragma unroll
        for (int r = 0; r < 4; ++r)
          C[(size_t)(mb + r) * 1024 + n] = acc[i][j][r] + bv;
      }
    }
  }
}

// ---------------------------------------------------------------------------
// psi transform on bf16 (in place), heads HALF..H-1; 4 rows per block.
// ---------------------------------------------------------------------------
__global__ __launch_bounds__(256) void psi_kernel(ushort_t* __restrict__ X,
                                                  float* __restrict__ Xn) {
  const int s = blockIdx.x * 4 + (threadIdx.x >> 6);
  const int hh = blockIdx.y, b = blockIdx.z;
  const int h = HALF + hh;
  ushort_t* row = X + (((size_t)b * H + h) * S + s) * DK;
  const int t = threadIdx.x & 63;
  const float v = bf2f(row[t]);
  const float last = __shfl(v, 63, 64);
  const float y = 1.0f / (1.0f + expf(-last));
  const float xv = (t < 63) ? v * y : y;
  const ushort_t bvv = f2bf(xv);
  row[t] = bvv;
  const float xr = bf2f(bvv);
  float sq = (t < 63) ? xr * xr : 0.0f;
#pragma unroll
  for (int off = 32; off; off >>= 1) sq += __shfl_xor(sq, off, 64);
  if (t == 0) Xn[((size_t)b * HALF + hh) * S + s] = sq;
}

// ---------------------------------------------------------------------------
// Flash attention, bf16 in / bf16 out.
// ---------------------------------------------------------------------------
__global__ __launch_bounds__(256) void attn_mfma(
    const ushort_t* __restrict__ Qf, const ushort_t* __restrict__ Kf,
    const ushort_t* __restrict__ Vt, const float* __restrict__ Qn,
    const float* __restrict__ Kn, ushort_t* __restrict__ O) {
  const int qb = blockIdx.x, h = blockIdx.y, b = blockIdx.z;
  const int tid = threadIdx.x, lane = tid & 63, wid = tid >> 6;
  const int lq = lane & 15, g = lane >> 4;
  const int qg = qb * 64 + wid * 16 + lq;
  const bool pen = (h >= HALF);
  const float slope = -exp2f(-0.5f * (float)(h + 1));
  const size_t hoff = ((size_t)b * H + h) * S * DK;
  const ushort_t* Vslab = Vt + hoff;  // [dk][s]

  __shared__ __align__(16) char sK[64 * 128];
  __shared__ __align__(16) char sV[64 * 128];
  __shared__ float sKn[64];
  __shared__ float sKy[64];

  const ushort_t* qrow = Qf + hoff + (size_t)qg * DK;
  short8v qfrag[2];
#pragma unroll
  for (int c = 0; c < 2; c++)
    qfrag[c] = *(const short8v*)(qrow + c * 32 + g * 8);

  float qy = 0.f, qnv = 0.f, qy2 = 0.f, xqy = 0.f;
  if (pen) {
    qy = bf2f(qrow[63]);
    qnv = Qn[((size_t)b * HALF + (h - HALF)) * S + qg];
    qy2 = qy * qy;
    xqy = sqrtf(1.0f - qy2 + 1e-6f);
  }

  f32x4 o[4];
#pragma unroll
  for (int dt = 0; dt < 4; dt++) o[dt] = (f32x4){0.f, 0.f, 0.f, 0.f};
  float m = -1e30f, lacc = 0.f;

  const int srow = tid >> 2, squad = tid & 3;

  for (int kt = 0; kt <= qb; ++kt) {
    {
      const ushort_t* ks = Kf + hoff + (size_t)(kt * 64 + srow) * DK + squad * 16;
      short8v k0v = *(const short8v*)(ks);
      short8v k1v = *(const short8v*)(ks + 8);
      if (pen && squad == 3) k1v[7] = 0;  // exclude y-elem from MFMA dot
      const int swz = (srow & 7) << 4;
      *(short8v*)(sK + srow * 128 + ((squad * 32) ^ swz)) = k0v;
      *(short8v*)(sK + srow * 128 + ((squad * 32 + 16) ^ swz)) = k1v;

      const ushort_t* vs = Vslab + (size_t)srow * S + kt * 64 + squad * 16;
      short8v v0 = *(const short8v*)(vs);
      short8v v1 = *(const short8v*)(vs + 8);
      *(short8v*)(sV + srow * 128 + ((squad * 32) ^ swz)) = v0;
      *(short8v*)(sV + srow * 128 + ((squad * 32 + 16) ^ swz)) = v1;

      if (pen) {
        if (tid < 64)
          sKn[tid] = Kn[((size_t)b * HALF + (h - HALF)) * S + kt * 64 + tid];
        else if (tid < 128)
          sKy[tid - 64] = bf2f(Kf[hoff + (size_t)(kt * 64 + tid - 64) * DK + 63]);
      }
    }
    __syncthreads();

    float p[4][4];
    float tmax = -1e30f;
#pragma unroll
    for (int t4 = 0; t4 < 4; ++t4) {
      f32x4 acc = (f32x4){0.f, 0.f, 0.f, 0.f};
#pragma unroll
      for (int c = 0; c < 2; ++c) {
        const int row = t4 * 16 + lq;
        const short8v ka = *(const short8v*)(
            sK + row * 128 + ((c * 64 + g * 16) ^ ((row & 7) << 4)));
        acc = __builtin_amdgcn_mfma_f32_16x16x32_bf16(ka, qfrag[c], acc, 0, 0, 0);
      }
      float4 kn4, ky4;
      if (pen) {
        kn4 = *(const float4*)(sKn + t4 * 16 + g * 4);
        ky4 = *(const float4*)(sKy + t4 * 16 + g * 4);
      }
#pragma unroll
      for (int r = 0; r < 4; ++r) {
        const int kg = kt * 64 + t4 * 16 + g * 4 + r;
        float s = -1e30f;
        if (kg < qg) {
          const float dot = acc[r];
          const float ab = slope * (float)(qg - kg);
          if (!pen) {
            s = dot * 0.125f + ab;
          } else {
            const float kn = ((const float*)&kn4)[r];
            const float ky = ((const float*)&ky4)[r];
            const float ky2 = ky * ky;
            const float d2 = qnv + kn - 2.0f * dot;
            const float pd = sqrtf(fmaxf(d2, 0.0f) + 1e-12f);
            const float xky = sqrtf(1.0f - ky2 + 1e-6f);
            const float tmp = (xqy + xky - pd) * 0.5f;
            const float lca = fmaxf(fmaxf(qy2, ky2), 1.0f - tmp * tmp);
            const float num = (pd * pd + ky2 - qy2) / (2.0f * pd + 1e-6f);
            const float lout = num * num + qy2;
            const float dxy = pd - xqy;
            const bool exists = (pd <= xqy) || (dxy * dxy + ky2 <= 1.0f);
            s = -0.1f * (exists ? lca : lout) * 0.125f + ab;
          }
        }
        p[t4][r] = s;
        tmax = fmaxf(tmax, s);
      }
    }
    tmax = fmaxf(tmax, __shfl_xor(tmax, 16, 64));
    tmax = fmaxf(tmax, __shfl_xor(tmax, 32, 64));
    const float mnew = fmaxf(m, tmax);
    const float fsc = __expf(m - mnew);
    float ls = 0.f;
#pragma unroll
    for (int t4 = 0; t4 < 4; ++t4)
#pragma unroll
      for (int r = 0; r < 4; ++r) {
        const float sc = p[t4][r];
        float pv = __expf(sc - mnew);
        if (sc < -1e29f) pv = 0.f;
        p[t4][r] = pv;
        ls += pv;
      }
    ls += __shfl_xor(ls, 16, 64);
    ls += __shfl_xor(ls, 32, 64);
    lacc = lacc * fsc + ls;
    m = mnew;
#pragma unroll
    for (int dt = 0; dt < 4; ++dt) o[dt] = o[dt] * fsc;

    unsigned pk0[4], pk1[4];
#pragma unroll
    for (int t4 = 0; t4 < 4; ++t4) {
      pk0[t4] = packbf(p[t4][0], p[t4][1]);
      pk1[t4] = packbf(p[t4][2], p[t4][3]);
    }
    const int s0 = lq | (((g * 2) & 3) << 4);
    const int s1 = lq | (((g * 2 + 1) & 3) << 4);
    const bool hi = (g >= 2);
#pragma unroll
    for (int c = 0; c < 2; ++c) {
      const unsigned a0 = (unsigned)__shfl((int)pk0[2 * c], s0, 64);
      const unsigned b0 = (unsigned)__shfl((int)pk0[2 * c + 1], s0, 64);
      const unsigned a1 = (unsigned)__shfl((int)pk1[2 * c], s0, 64);
      const unsigned b1 = (unsigned)__shfl((int)pk1[2 * c + 1], s0, 64);
      const unsigned a2 = (unsigned)__shfl((int)pk0[2 * c], s1, 64);
      const unsigned b2 = (unsigned)__shfl((int)pk0[2 * c + 1], s1, 64);
      const unsigned a3 = (unsigned)__shfl((int)pk1[2 * c], s1, 64);
      const unsigned b3 = (unsigned)__shfl((int)pk1[2 * c + 1], s1, 64);
      union { short8v v; unsigned u[4]; } pb;
      pb.u[0] = hi ? b0 : a0;
      pb.u[1] = hi ? b1 : a1;
      pb.u[2] = hi ? b2 : a2;
      pb.u[3] = hi ? b3 : a3;
#pragma unroll
      for (int dt = 0; dt < 4; ++dt) {
        const int vr = dt * 16 + lq;
        const short8v va = *(const short8v*)(
            sV + vr * 128 + ((c * 64 + g * 16) ^ ((vr & 7) << 4)));
        o[dt] = __builtin_amdgcn_mfma_f32_16x16x32_bf16(va, pb.v, o[dt], 0, 0, 0);
      }
    }
    __syncthreads();
  }

  const float invl = (qg == 0) ? 0.f : 1.0f / lacc;
  ushort_t* orow = O + ((size_t)b * S + qg) * D + h * DK;
#pragma unroll
  for (int dt = 0; dt < 4; ++dt) {
    uint2 u;
    u.x = packbf(o[dt][0] * invl, o[dt][1] * invl);
    u.y = packbf(o[dt][2] * invl, o[dt][3] * invl);
    *(uint2*)(orow + dt * 16 + g * 4) = u;
  }
}

// ---------------------------------------------------------------------------
extern "C" void kernel_launch(void* const* d_in, const int* in_sizes, int n_in,
                              void* d_out, int out_size, void* d_ws,
                              size_t ws_size, hipStream_t stream) {
  (void)in_sizes; (void)n_in; (void)out_size; (void)ws_size;
  const float* x  = (const float*)d_in[0];
  const float* Wq = (const float*)d_in[1];
  const float* bq = (const float*)d_in[2];
  const float* Wk = (const float*)d_in[3];
  const float* bk = (const float*)d_in[4];
  const float* Wv = (const float*)d_in[5];
  const float* bv = (const float*)d_in[6];
  const float* Wo = (const float*)d_in[7];
  const float* bo = (const float*)d_in[8];
  float* out = (float*)d_out;

  const size_t NQKV = (size_t)BS * H * S * DK;  // 8388608
  const size_t NW = (size_t)D * D;              // 1048576
  ushort_t* ws  = (ushort_t*)d_ws;
  ushort_t* Qb  = ws;
  ushort_t* Kbb = Qb + NQKV;
  ushort_t* Vtb = Kbb + NQKV;
  ushort_t* Ob  = Vtb + NQKV;
  ushort_t* xb  = Ob + NQKV;
  ushort_t* Wqb = xb + NQKV;
  ushort_t* Wkb = Wqb + NW;
  ushort_t* Wvb = Wkb + NW;
  ushort_t* Wob = Wvb + NW;
  float* Qn = (float*)(Wob + NW);
  float* Kn = Qn + (size_t)BS * HALF * S;

  cvt_bf16<<<dim3(4096), 256, 0, stream>>>(x, xb, (int)(NQKV / 8));
  cvt_bf16<<<dim3(512), 256, 0, stream>>>(Wq, Wqb, (int)(NW / 8));
  cvt_bf16<<<dim3(512), 256, 0, stream>>>(Wk, Wkb, (int)(NW / 8));
  cvt_bf16<<<dim3(512), 256, 0, stream>>>(Wv, Wvb, (int)(NW / 8));
  cvt_bf16<<<dim3(512), 256, 0, stream>>>(Wo, Wob, (int)(NW / 8));

  dim3 gg(8, 64);  // N/128, M/128
  gemm_mfma<0><<<gg, 256, 0, stream>>>(xb, Wqb, bq, Qb);
  gemm_mfma<0><<<gg, 256, 0, stream>>>(xb, Wkb, bk, Kbb);
  gemm_mfma<1><<<gg, 256, 0, stream>>>(xb, Wvb, bv, Vtb);
  psi_kernel<<<dim3(S / 4, HALF, BS), 256, 0, stream>>>(Qb, Qn);
  psi_kernel<<<dim3(S / 4, HALF, BS), 256, 0, stream>>>(Kbb, Kn);
  attn_mfma<<<dim3(S / 64, H, BS), 256, 0, stream>>>(Qb, Kbb, Vtb, Qn, Kn, Ob);
  gemm_mfma<2><<<gg, 256, 0, stream>>>(Ob, Wob, bo, out);
}

// Round 4
// 233.384 us; speedup vs baseline: 14.5660x; 1.1664x over previous
//
#include <hip/hip_runtime.h>
#include <math.h>

#define BS 16
#define S 512
#define D 1024
#define H 16
#define DK 64
#define HALF 8

typedef __attribute__((ext_vector_type(8))) short short8v;
typedef __attribute__((ext_vector_type(4))) float f32x4;
typedef unsigned short ushort_t;

__device__ __forceinline__ ushort_t f2bf(float f) {
  union { float f; unsigned u; } v; v.f = f;
  unsigned r = v.u + 0x7fffu + ((v.u >> 16) & 1u);
  return (ushort_t)(r >> 16);
}
__device__ __forceinline__ unsigned packbf(float a, float b) {
  return (unsigned)f2bf(a) | ((unsigned)f2bf(b) << 16);
}
__device__ __forceinline__ float bf2f(ushort_t u) {
  union { unsigned u; float f; } v; v.u = ((unsigned)u) << 16;
  return v.f;
}
__device__ __forceinline__ unsigned cvtpk(float lo, float hi) {
  unsigned r;
  asm("v_cvt_pk_bf16_f32 %0, %1, %2" : "=v"(r) : "v"(lo), "v"(hi));
  return r;
}

__device__ __forceinline__ void gload16(const void* g, void* l) {
  __builtin_amdgcn_global_load_lds(
      (const __attribute__((address_space(1))) unsigned int*)g,
      (__attribute__((address_space(3))) unsigned int*)l, 16, 0, 0);
}

// ---------------------------------------------------------------------------
// f32 -> bf16 convert, 8 elems/thread
// ---------------------------------------------------------------------------
__global__ __launch_bounds__(256) void cvt_bf16(const float* __restrict__ in,
                                                ushort_t* __restrict__ out,
                                                int n8) {
  const int i = blockIdx.x * 256 + threadIdx.x;
  if (i >= n8) return;
  const float4 a = *(const float4*)(in + (size_t)i * 8);
  const float4 b = *(const float4*)(in + (size_t)i * 8 + 4);
  union { short8v v; unsigned u[4]; } t;
  t.u[0] = packbf(a.x, a.y);
  t.u[1] = packbf(a.z, a.w);
  t.u[2] = packbf(b.x, b.y);
  t.u[3] = packbf(b.z, b.w);
  *(short8v*)(out + (size_t)i * 8) = t.v;
}

// ---------------------------------------------------------------------------
// bf16 MFMA GEMM (unchanged from R3): C[8192,1024] = A * B^T + bias
// ---------------------------------------------------------------------------
template <int EPI>
__global__ __launch_bounds__(256) void gemm_mfma(
    const ushort_t* __restrict__ A, const ushort_t* __restrict__ B,
    const float* __restrict__ bias, void* __restrict__ Cout) {
  const int tid = threadIdx.x;
  const int lane = tid & 63, wid = tid >> 6;
  const int wr = wid >> 1, wc = wid & 1;
  const int lq = lane & 15, g = lane >> 4;
  const int bn = blockIdx.x;
  const int bm = blockIdx.y;

  __shared__ __align__(16) ushort_t sA[128 * 64];
  __shared__ __align__(16) ushort_t sB[128 * 64];

  f32x4 acc[4][4];
#pragma unroll
  for (int i = 0; i < 4; i++)
#pragma unroll
    for (int j = 0; j < 4; j++) acc[i][j] = (f32x4){0.f, 0.f, 0.f, 0.f};

  for (int k0 = 0; k0 < 1024; k0 += 64) {
#pragma unroll
    for (int is = 0; is < 4; ++is) {
      const int gi = is * 256 + tid;
      const int row = gi >> 3, slot = gi & 7;
      const int sslot = slot ^ (row & 7);
      const ushort_t* srcA =
          A + (size_t)(bm * 128 + row) * 1024 + k0 + sslot * 8;
      const ushort_t* srcB =
          B + (size_t)(bn * 128 + row) * 1024 + k0 + sslot * 8;
      gload16(srcA, &sA[(is * 256 + wid * 64) * 8]);
      gload16(srcB, &sB[(is * 256 + wid * 64) * 8]);
    }
    __syncthreads();
#pragma unroll
    for (int ks = 0; ks < 2; ++ks) {
      short8v af[4], bf[4];
#pragma unroll
      for (int i = 0; i < 4; ++i) {
        const int arow = wr * 64 + i * 16 + lq;
        af[i] = *(const short8v*)&sA[arow * 64 + (((ks * 4 + g) ^ (arow & 7)) * 8)];
        const int brow = wc * 64 + i * 16 + lq;
        bf[i] = *(const short8v*)&sB[brow * 64 + (((ks * 4 + g) ^ (brow & 7)) * 8)];
      }
#pragma unroll
      for (int i = 0; i < 4; ++i)
#pragma unroll
        for (int j = 0; j < 4; ++j)
          acc[i][j] =
              __builtin_amdgcn_mfma_f32_16x16x32_bf16(af[i], bf[j], acc[i][j], 0, 0, 0);
    }
    __syncthreads();
  }

#pragma unroll
  for (int j = 0; j < 4; ++j) {
    const int n = bn * 128 + wc * 64 + j * 16 + lq;
    const float bv = bias[n];
#pragma unroll
    for (int i = 0; i < 4; ++i) {
      const int mb = bm * 128 + wr * 64 + i * 16 + g * 4;
      if (EPI == 0) {
        ushort_t* C = (ushort_t*)Cout;
#pragma unroll
        for (int r = 0; r < 4; ++r) {
          const int m = mb + r;
          const float c = acc[i][j][r] + bv;
          C[((((size_t)(m >> 9) * H + (n >> 6)) * S + (m & 511)) * DK) +
            (n & 63)] = f2bf(c);
        }
      } else if (EPI == 1) {
        ushort_t* C = (ushort_t*)Cout;
        const int bb = mb >> 9, s0 = mb & 511;
        uint2 u;
        u.x = packbf(acc[i][j][0] + bv, acc[i][j][1] + bv);
        u.y = packbf(acc[i][j][2] + bv, acc[i][j][3] + bv);
        *(uint2*)(C + (((size_t)bb * H + (n >> 6)) * DK + (n & 63)) * S + s0) = u;
      } else {
        float* C = (float*)Cout;
#pragma unroll
        for (int r = 0; r < 4; ++r)
          C[(size_t)(mb + r) * 1024 + n] = acc[i][j][r] + bv;
      }
    }
  }
}

// ---------------------------------------------------------------------------
// psi transform on bf16 (in place), heads HALF..H-1; emits per-row float4
// (sum(x^2, d<63), y^2, sqrt(1-y^2+eps), 0) for the penumbral score math.
// ---------------------------------------------------------------------------
__global__ __launch_bounds__(256) void psi_kernel(ushort_t* __restrict__ X,
                                                  float4* __restrict__ Pn) {
  const int s = blockIdx.x * 4 + (threadIdx.x >> 6);
  const int hh = blockIdx.y, b = blockIdx.z;
  const int h = HALF + hh;
  ushort_t* row = X + (((size_t)b * H + h) * S + s) * DK;
  const int t = threadIdx.x & 63;
  const float v = bf2f(row[t]);
  const float last = __shfl(v, 63, 64);
  const float y = 1.0f / (1.0f + expf(-last));
  const float xv = (t < 63) ? v * y : y;
  const ushort_t bvv = f2bf(xv);
  row[t] = bvv;
  const float xr = bf2f(bvv);
  float sq = (t < 63) ? xr * xr : 0.0f;
#pragma unroll
  for (int off = 32; off; off >>= 1) sq += __shfl_xor(sq, off, 64);
  if (t == 0)
    Pn[((size_t)b * HALF + hh) * S + s] =
        make_float4(sq, y * y, sqrtf(1.0f - y * y + 1e-6f), 0.0f);
}

// ---------------------------------------------------------------------------
// One q-tile update vs the currently staged 64-k tile.
// ---------------------------------------------------------------------------
__device__ __forceinline__ void attn_tile(
    const char* sKb, const char* sVb, const float4* sPn, const short8v* qf,
    float qn, float qy2, float xqy, bool pen, float slope, int qg, int kt0,
    int lq, int g, f32x4* o, float& m, float& lacc) {
  float p[4][4];
  float tmax = -1e30f;
#pragma unroll
  for (int t4 = 0; t4 < 4; ++t4) {
    f32x4 acc = (f32x4){0.f, 0.f, 0.f, 0.f};
    const int row = t4 * 16 + lq;
#pragma unroll
    for (int c = 0; c < 2; ++c) {
      const short8v ka =
          *(const short8v*)(sKb + row * 128 + (((c * 4 + g) ^ (row & 7)) * 16));
      acc = __builtin_amdgcn_mfma_f32_16x16x32_bf16(ka, qf[c], acc, 0, 0, 0);
    }
#pragma unroll
    for (int r = 0; r < 4; ++r) {
      const int kg = kt0 + t4 * 16 + g * 4 + r;
      const float ab = slope * (float)(qg - kg);
      float s;
      if (!pen) {
        s = acc[r] * 0.125f + ab;
      } else {
        const float4 kp = sPn[t4 * 16 + g * 4 + r];
        const float kn = kp.x, ky2 = kp.y, xky = kp.z;
        const float d2 = qn + kn - 2.0f * acc[r];
        const float tt = d2 + 1e-12f;
        const float rs = rsqrtf(tt);
        const float pd = tt * rs;  // = sqrt(tt)
        const float tmp = (xqy + xky - pd) * 0.5f;
        const float lca = fmaxf(fmaxf(qy2, ky2), 1.0f - tmp * tmp);
        const float num = (d2 + ky2 - qy2) * (0.5f * rs);
        const float lout = num * num + qy2;
        const float dxy = pd - xqy;
        const bool ex = (pd <= xqy) || (dxy * dxy + ky2 <= 1.0f);
        s = (ex ? lca : lout) * -0.0125f + ab;
      }
      if (kg >= qg) s = -1e30f;
      p[t4][r] = s;
      tmax = fmaxf(tmax, s);
    }
  }
  tmax = fmaxf(tmax, __shfl_xor(tmax, 16, 64));
  tmax = fmaxf(tmax, __shfl_xor(tmax, 32, 64));
  const float mnew = fmaxf(m, tmax);
  if (__any(mnew > m)) {  // descending-kt: diagonal first, so usually skipped
    const float fsc = __expf(m - mnew);
#pragma unroll
    for (int dt = 0; dt < 4; ++dt) o[dt] *= fsc;
    lacc *= fsc;
    m = mnew;
  }
  float ls = 0.f;
#pragma unroll
  for (int t4 = 0; t4 < 4; ++t4)
#pragma unroll
    for (int r = 0; r < 4; ++r) {
      float pv = __expf(p[t4][r] - m);
      if (p[t4][r] < -1e29f) pv = 0.f;
      p[t4][r] = pv;
      ls += pv;
    }
  ls += __shfl_xor(ls, 16, 64);
  ls += __shfl_xor(ls, 32, 64);
  lacc += ls;

  unsigned pk0[4], pk1[4];
#pragma unroll
  for (int t4 = 0; t4 < 4; ++t4) {
    pk0[t4] = cvtpk(p[t4][0], p[t4][1]);
    pk1[t4] = cvtpk(p[t4][2], p[t4][3]);
  }
  const int s0 = lq | (((g * 2) & 3) << 4);
  const int s1 = lq | (((g * 2 + 1) & 3) << 4);
  const bool hi = (g >= 2);
#pragma unroll
  for (int c = 0; c < 2; ++c) {
    const unsigned a0 = (unsigned)__shfl((int)pk0[2 * c], s0, 64);
    const unsigned b0 = (unsigned)__shfl((int)pk0[2 * c + 1], s0, 64);
    const unsigned a1 = (unsigned)__shfl((int)pk1[2 * c], s0, 64);
    const unsigned b1 = (unsigned)__shfl((int)pk1[2 * c + 1], s0, 64);
    const unsigned a2 = (unsigned)__shfl((int)pk0[2 * c], s1, 64);
    const unsigned b2 = (unsigned)__shfl((int)pk0[2 * c + 1], s1, 64);
    const unsigned a3 = (unsigned)__shfl((int)pk1[2 * c], s1, 64);
    const unsigned b3 = (unsigned)__shfl((int)pk1[2 * c + 1], s1, 64);
    union { short8v v; unsigned u[4]; } pb;
    pb.u[0] = hi ? b0 : a0;
    pb.u[1] = hi ? b1 : a1;
    pb.u[2] = hi ? b2 : a2;
    pb.u[3] = hi ? b3 : a3;
#pragma unroll
    for (int dt = 0; dt < 4; ++dt) {
      const int vr = dt * 16 + lq;
      const short8v va =
          *(const short8v*)(sVb + vr * 128 + (((c * 4 + g) ^ (vr & 7)) * 16));
      o[dt] = __builtin_amdgcn_mfma_f32_16x16x32_bf16(va, pb.v, o[dt], 0, 0, 0);
    }
  }
}

// ---------------------------------------------------------------------------
// Flash attention: block = (q-pair qp/{7-qp}, h, b). 4 waves x 16 q-rows,
// descending causal k-tiles shared by both q-tiles. Double-buffered
// global_load_lds staging (linear LDS dest, pre-swizzled global source).
// ---------------------------------------------------------------------------
__global__ __launch_bounds__(256, 4) void attn_mfma(
    const ushort_t* __restrict__ Qf, const ushort_t* __restrict__ Kf,
    const ushort_t* __restrict__ Vt, const float4* __restrict__ QPn,
    const float4* __restrict__ KPn, ushort_t* __restrict__ O) {
  const int qp = blockIdx.x, h = blockIdx.y, b = blockIdx.z;
  const int tid = threadIdx.x, lane = tid & 63, wid = tid >> 6;
  const int lq = lane & 15, g = lane >> 4;
  const bool pen = (h >= HALF);
  const float slope = -exp2f(-0.5f * (float)(h + 1));
  const size_t hoff = ((size_t)b * H + h) * S * DK;
  const ushort_t* Vslab = Vt + hoff;  // [dk][s] bf16
  const size_t bhh = (size_t)b * HALF + (h & (HALF - 1));

  __shared__ __align__(16) char sK[2][8192];
  __shared__ __align__(16) char sV[2][8192];
  __shared__ __align__(16) float4 sPen[2][64];

  const int qb_hi = 7 - qp, qb_lo = qp;
  const int qgH = qb_hi * 64 + wid * 16 + lq;
  const int qgL = qb_lo * 64 + wid * 16 + lq;

  short8v qfH[2], qfL[2];
  {
    const ushort_t* qr = Qf + hoff + (size_t)qgH * DK;
    qfH[0] = *(const short8v*)(qr + g * 8);
    qfH[1] = *(const short8v*)(qr + 32 + g * 8);
    qr = Qf + hoff + (size_t)qgL * DK;
    qfL[0] = *(const short8v*)(qr + g * 8);
    qfL[1] = *(const short8v*)(qr + 32 + g * 8);
    if (pen && g == 3) { qfH[1][7] = 0; qfL[1][7] = 0; }  // drop y from dot
  }
  float qnH = 0, qy2H = 0, xqyH = 0, qnL = 0, qy2L = 0, xqyL = 0;
  if (pen) {
    const float4 a = QPn[bhh * S + qgH];
    qnH = a.x; qy2H = a.y; xqyH = a.z;
    const float4 c = QPn[bhh * S + qgL];
    qnL = c.x; qy2L = c.y; xqyL = c.z;
  }

  const int r8 = lane >> 3;
  const int sl = ((lane & 7) ^ r8) * 8;  // pre-swizzled 16B-granule offset

  auto stage = [&](int buf, int kt) {
#pragma unroll
    for (int i = 0; i < 2; ++i) {
      const int row = wid * 16 + i * 8 + r8;
      gload16(Kf + hoff + (size_t)(kt * 64 + row) * DK + sl,
              &sK[buf][(wid * 2 + i) * 1024]);
      gload16(Vslab + (size_t)row * S + kt * 64 + sl,
              &sV[buf][(wid * 2 + i) * 1024]);
    }
    if (pen && wid == 0)
      gload16(&KPn[bhh * S + kt * 64 + lane], &sPen[buf][0]);
  };

  f32x4 oH[4], oL[4];
#pragma unroll
  for (int dt = 0; dt < 4; ++dt) {
    oH[dt] = (f32x4){0.f, 0.f, 0.f, 0.f};
    oL[dt] = (f32x4){0.f, 0.f, 0.f, 0.f};
  }
  float mH = -1e30f, lH = 0.f, mL = -1e30f, lL = 0.f;

  stage(0, qb_hi);
  __syncthreads();
  int cur = 0;
  for (int kt = qb_hi; kt >= 0; --kt) {
    if (kt > 0) stage(cur ^ 1, kt - 1);
    attn_tile(sK[cur], sV[cur], sPen[cur], qfH, qnH, qy2H, xqyH, pen, slope,
              qgH, kt * 64, lq, g, oH, mH, lH);
    if (kt <= qb_lo)
      attn_tile(sK[cur], sV[cur], sPen[cur], qfL, qnL, qy2L, xqyL, pen, slope,
                qgL, kt * 64, lq, g, oL, mL, lL);
    __syncthreads();  // drains vmcnt: next buffer complete, cur free to reuse
    cur ^= 1;
  }

  const float invH = 1.0f / lH;  // qgH >= 256, always nonzero
  const float invL = (qgL == 0) ? 0.f : 1.0f / lL;
  ushort_t* orH = O + ((size_t)b * S + qgH) * D + h * DK;
  ushort_t* orL = O + ((size_t)b * S + qgL) * D + h * DK;
#pragma unroll
  for (int dt = 0; dt < 4; ++dt) {
    uint2 u;
    u.x = cvtpk(oH[dt][0] * invH, oH[dt][1] * invH);
    u.y = cvtpk(oH[dt][2] * invH, oH[dt][3] * invH);
    *(uint2*)(orH + dt * 16 + g * 4) = u;
    uint2 v;
    v.x = cvtpk(oL[dt][0] * invL, oL[dt][1] * invL);
    v.y = cvtpk(oL[dt][2] * invL, oL[dt][3] * invL);
    *(uint2*)(orL + dt * 16 + g * 4) = v;
  }
}

// ---------------------------------------------------------------------------
extern "C" void kernel_launch(void* const* d_in, const int* in_sizes, int n_in,
                              void* d_out, int out_size, void* d_ws,
                              size_t ws_size, hipStream_t stream) {
  (void)in_sizes; (void)n_in; (void)out_size; (void)ws_size;
  const float* x  = (const float*)d_in[0];
  const float* Wq = (const float*)d_in[1];
  const float* bq = (const float*)d_in[2];
  const float* Wk = (const float*)d_in[3];
  const float* bk = (const float*)d_in[4];
  const float* Wv = (const float*)d_in[5];
  const float* bv = (const float*)d_in[6];
  const float* Wo = (const float*)d_in[7];
  const float* bo = (const float*)d_in[8];
  float* out = (float*)d_out;

  const size_t NQKV = (size_t)BS * H * S * DK;  // 8388608
  const size_t NW = (size_t)D * D;              // 1048576
  ushort_t* ws  = (ushort_t*)d_ws;
  ushort_t* Qb  = ws;
  ushort_t* Kbb = Qb + NQKV;
  ushort_t* Vtb = Kbb + NQKV;
  ushort_t* Ob  = Vtb + NQKV;
  ushort_t* xb  = Ob + NQKV;
  ushort_t* Wqb = xb + NQKV;
  ushort_t* Wkb = Wqb + NW;
  ushort_t* Wvb = Wkb + NW;
  ushort_t* Wob = Wvb + NW;
  float4* QPn = (float4*)(Wob + NW);  // 16B aligned (offset 92274688 bytes)
  float4* KPn = QPn + (size_t)BS * HALF * S;

  cvt_bf16<<<dim3(4096), 256, 0, stream>>>(x, xb, (int)(NQKV / 8));
  cvt_bf16<<<dim3(512), 256, 0, stream>>>(Wq, Wqb, (int)(NW / 8));
  cvt_bf16<<<dim3(512), 256, 0, stream>>>(Wk, Wkb, (int)(NW / 8));
  cvt_bf16<<<dim3(512), 256, 0, stream>>>(Wv, Wvb, (int)(NW / 8));
  cvt_bf16<<<dim3(512), 256, 0, stream>>>(Wo, Wob, (int)(NW / 8));

  dim3 gg(8, 64);
  gemm_mfma<0><<<gg, 256, 0, stream>>>(xb, Wqb, bq, Qb);
  gemm_mfma<0><<<gg, 256, 0, stream>>>(xb, Wkb, bk, Kbb);
  gemm_mfma<1><<<gg, 256, 0, stream>>>(xb, Wvb, bv, Vtb);
  psi_kernel<<<dim3(S / 4, HALF, BS), 256, 0, stream>>>(Qb, QPn);
  psi_kernel<<<dim3(S / 4, HALF, BS), 256, 0, stream>>>(Kbb, KPn);
  attn_mfma<<<dim3(4, H, BS), 256, 0, stream>>>(Qb, Kbb, Vtb, QPn, KPn, Ob);
  gemm_mfma<2><<<gg, 256, 0, stream>>>(Ob, Wob, bo, out);
}

// Round 5
// 223.396 us; speedup vs baseline: 15.2173x; 1.0447x over previous
//
#include <hip/hip_runtime.h>
#include <math.h>

#define BS 16
#define S 512
#define D 1024
#define H 16
#define DK 64
#define HALF 8

typedef __attribute__((ext_vector_type(8))) short short8v;
typedef __attribute__((ext_vector_type(4))) float f32x4;
typedef unsigned short ushort_t;

__device__ __forceinline__ ushort_t f2bf(float f) {
  union { float f; unsigned u; } v; v.f = f;
  unsigned r = v.u + 0x7fffu + ((v.u >> 16) & 1u);
  return (ushort_t)(r >> 16);
}
__device__ __forceinline__ unsigned packbf(float a, float b) {
  return (unsigned)f2bf(a) | ((unsigned)f2bf(b) << 16);
}
__device__ __forceinline__ float bf2f(ushort_t u) {
  union { unsigned u; float f; } v; v.u = ((unsigned)u) << 16;
  return v.f;
}
__device__ __forceinline__ unsigned cvtpk(float lo, float hi) {
  unsigned r;
  asm("v_cvt_pk_bf16_f32 %0, %1, %2" : "=v"(r) : "v"(lo), "v"(hi));
  return r;
}

__device__ __forceinline__ void gload16(const void* g, void* l) {
  __builtin_amdgcn_global_load_lds(
      (const __attribute__((address_space(1))) unsigned int*)g,
      (__attribute__((address_space(3))) unsigned int*)l, 16, 0, 0);
}

// ---------------------------------------------------------------------------
// f32 -> bf16 convert, 8 elems/thread
// ---------------------------------------------------------------------------
__global__ __launch_bounds__(256) void cvt_bf16(const float* __restrict__ in,
                                                ushort_t* __restrict__ out,
                                                int n8) {
  const int i = blockIdx.x * 256 + threadIdx.x;
  if (i >= n8) return;
  const float4 a = *(const float4*)(in + (size_t)i * 8);
  const float4 b = *(const float4*)(in + (size_t)i * 8 + 4);
  union { short8v v; unsigned u[4]; } t;
  t.u[0] = packbf(a.x, a.y);
  t.u[1] = packbf(a.z, a.w);
  t.u[2] = packbf(b.x, b.y);
  t.u[3] = packbf(b.z, b.w);
  *(short8v*)(out + (size_t)i * 8) = t.v;
}

// ---------------------------------------------------------------------------
// bf16 MFMA GEMM (unchanged): C[8192,1024] = A * B^T + bias
// ---------------------------------------------------------------------------
template <int EPI>
__global__ __launch_bounds__(256) void gemm_mfma(
    const ushort_t* __restrict__ A, const ushort_t* __restrict__ B,
    const float* __restrict__ bias, void* __restrict__ Cout) {
  const int tid = threadIdx.x;
  const int lane = tid & 63, wid = tid >> 6;
  const int wr = wid >> 1, wc = wid & 1;
  const int lq = lane & 15, g = lane >> 4;
  const int bn = blockIdx.x;
  const int bm = blockIdx.y;

  __shared__ __align__(16) ushort_t sA[128 * 64];
  __shared__ __align__(16) ushort_t sB[128 * 64];

  f32x4 acc[4][4];
#pragma unroll
  for (int i = 0; i < 4; i++)
#pragma unroll
    for (int j = 0; j < 4; j++) acc[i][j] = (f32x4){0.f, 0.f, 0.f, 0.f};

  for (int k0 = 0; k0 < 1024; k0 += 64) {
#pragma unroll
    for (int is = 0; is < 4; ++is) {
      const int gi = is * 256 + tid;
      const int row = gi >> 3, slot = gi & 7;
      const int sslot = slot ^ (row & 7);
      const ushort_t* srcA =
          A + (size_t)(bm * 128 + row) * 1024 + k0 + sslot * 8;
      const ushort_t* srcB =
          B + (size_t)(bn * 128 + row) * 1024 + k0 + sslot * 8;
      gload16(srcA, &sA[(is * 256 + wid * 64) * 8]);
      gload16(srcB, &sB[(is * 256 + wid * 64) * 8]);
    }
    __syncthreads();
#pragma unroll
    for (int ks = 0; ks < 2; ++ks) {
      short8v af[4], bf[4];
#pragma unroll
      for (int i = 0; i < 4; ++i) {
        const int arow = wr * 64 + i * 16 + lq;
        af[i] = *(const short8v*)&sA[arow * 64 + (((ks * 4 + g) ^ (arow & 7)) * 8)];
        const int brow = wc * 64 + i * 16 + lq;
        bf[i] = *(const short8v*)&sB[brow * 64 + (((ks * 4 + g) ^ (brow & 7)) * 8)];
      }
#pragma unroll
      for (int i = 0; i < 4; ++i)
#pragma unroll
        for (int j = 0; j < 4; ++j)
          acc[i][j] =
              __builtin_amdgcn_mfma_f32_16x16x32_bf16(af[i], bf[j], acc[i][j], 0, 0, 0);
    }
    __syncthreads();
  }

#pragma unroll
  for (int j = 0; j < 4; ++j) {
    const int n = bn * 128 + wc * 64 + j * 16 + lq;
    const float bv = bias[n];
#pragma unroll
    for (int i = 0; i < 4; ++i) {
      const int mb = bm * 128 + wr * 64 + i * 16 + g * 4;
      if (EPI == 0) {
        ushort_t* C = (ushort_t*)Cout;
#pragma unroll
        for (int r = 0; r < 4; ++r) {
          const int m = mb + r;
          const float c = acc[i][j][r] + bv;
          C[((((size_t)(m >> 9) * H + (n >> 6)) * S + (m & 511)) * DK) +
            (n & 63)] = f2bf(c);
        }
      } else if (EPI == 1) {
        ushort_t* C = (ushort_t*)Cout;
        const int bb = mb >> 9, s0 = mb & 511;
        uint2 u;
        u.x = packbf(acc[i][j][0] + bv, acc[i][j][1] + bv);
        u.y = packbf(acc[i][j][2] + bv, acc[i][j][3] + bv);
        *(uint2*)(C + (((size_t)bb * H + (n >> 6)) * DK + (n & 63)) * S + s0) = u;
      } else {
        float* C = (float*)Cout;
#pragma unroll
        for (int r = 0; r < 4; ++r)
          C[(size_t)(mb + r) * 1024 + n] = acc[i][j][r] + bv;
      }
    }
  }
}

// ---------------------------------------------------------------------------
// psi transform on bf16 (in place), heads HALF..H-1; emits per-row float4
// (sum(x^2, d<63), y^2, sqrt(1-y^2+eps), 0) for the penumbral score math.
// ---------------------------------------------------------------------------
__global__ __launch_bounds__(256) void psi_kernel(ushort_t* __restrict__ X,
                                                  float4* __restrict__ Pn) {
  const int s = blockIdx.x * 4 + (threadIdx.x >> 6);
  const int hh = blockIdx.y, b = blockIdx.z;
  const int h = HALF + hh;
  ushort_t* row = X + (((size_t)b * H + h) * S + s) * DK;
  const int t = threadIdx.x & 63;
  const float v = bf2f(row[t]);
  const float last = __shfl(v, 63, 64);
  const float y = 1.0f / (1.0f + expf(-last));
  const float xv = (t < 63) ? v * y : y;
  const ushort_t bvv = f2bf(xv);
  row[t] = bvv;
  const float xr = bf2f(bvv);
  float sq = (t < 63) ? xr * xr : 0.0f;
#pragma unroll
  for (int off = 32; off; off >>= 1) sq += __shfl_xor(sq, off, 64);
  if (t == 0)
    Pn[((size_t)b * HALF + hh) * S + s] =
        make_float4(sq, y * y, sqrtf(1.0f - y * y + 1e-6f), 0.0f);
}

// ---------------------------------------------------------------------------
// One q-tile update vs the currently staged 64-k tile.
// ---------------------------------------------------------------------------
__device__ __forceinline__ void attn_tile(
    const char* sKb, const char* sVb, const float4* sPn, const short8v* qf,
    float qn, float qy2, float xqy, bool pen, float slope, int qg, int kt0,
    int lq, int g, f32x4* o, float& m, float& lacc) {
  float p[4][4];
  float tmax = -1e30f;
#pragma unroll
  for (int t4 = 0; t4 < 4; ++t4) {
    f32x4 acc = (f32x4){0.f, 0.f, 0.f, 0.f};
    const int row = t4 * 16 + lq;
#pragma unroll
    for (int c = 0; c < 2; ++c) {
      const short8v ka =
          *(const short8v*)(sKb + row * 128 + (((c * 4 + g) ^ (row & 7)) * 16));
      acc = __builtin_amdgcn_mfma_f32_16x16x32_bf16(ka, qf[c], acc, 0, 0, 0);
    }
#pragma unroll
    for (int r = 0; r < 4; ++r) {
      const int kg = kt0 + t4 * 16 + g * 4 + r;
      const float ab = slope * (float)(qg - kg);
      float s;
      if (!pen) {
        s = acc[r] * 0.125f + ab;
      } else {
        const float4 kp = sPn[t4 * 16 + g * 4 + r];
        const float kn = kp.x, ky2 = kp.y, xky = kp.z;
        const float d2 = qn + kn - 2.0f * acc[r];
        const float tt = d2 + 1e-12f;
        const float rs = rsqrtf(tt);
        const float pd = tt * rs;  // = sqrt(tt)
        const float tmp = (xqy + xky - pd) * 0.5f;
        const float lca = fmaxf(fmaxf(qy2, ky2), 1.0f - tmp * tmp);
        const float num = (d2 + ky2 - qy2) * (0.5f * rs);
        const float lout = num * num + qy2;
        const float dxy = pd - xqy;
        const bool ex = (pd <= xqy) || (dxy * dxy + ky2 <= 1.0f);
        s = (ex ? lca : lout) * -0.0125f + ab;
      }
      if (kg >= qg) s = -1e30f;
      p[t4][r] = s;
      tmax = fmaxf(tmax, s);
    }
  }
  tmax = fmaxf(tmax, __shfl_xor(tmax, 16, 64));
  tmax = fmaxf(tmax, __shfl_xor(tmax, 32, 64));
  const float mnew = fmaxf(m, tmax);
  if (__any(mnew > m)) {  // descending-kt: diagonal first, so usually skipped
    const float fsc = __expf(m - mnew);
#pragma unroll
    for (int dt = 0; dt < 4; ++dt) o[dt] *= fsc;
    lacc *= fsc;
    m = mnew;
  }
  float ls = 0.f;
#pragma unroll
  for (int t4 = 0; t4 < 4; ++t4)
#pragma unroll
    for (int r = 0; r < 4; ++r) {
      float pv = __expf(p[t4][r] - m);
      if (p[t4][r] < -1e29f) pv = 0.f;
      p[t4][r] = pv;
      ls += pv;
    }
  ls += __shfl_xor(ls, 16, 64);
  ls += __shfl_xor(ls, 32, 64);
  lacc += ls;

  unsigned pk0[4], pk1[4];
#pragma unroll
  for (int t4 = 0; t4 < 4; ++t4) {
    pk0[t4] = cvtpk(p[t4][0], p[t4][1]);
    pk1[t4] = cvtpk(p[t4][2], p[t4][3]);
  }
  const int s0 = lq | (((g * 2) & 3) << 4);
  const int s1 = lq | (((g * 2 + 1) & 3) << 4);
  const bool hi = (g >= 2);
#pragma unroll
  for (int c = 0; c < 2; ++c) {
    const unsigned a0 = (unsigned)__shfl((int)pk0[2 * c], s0, 64);
    const unsigned b0 = (unsigned)__shfl((int)pk0[2 * c + 1], s0, 64);
    const unsigned a1 = (unsigned)__shfl((int)pk1[2 * c], s0, 64);
    const unsigned b1 = (unsigned)__shfl((int)pk1[2 * c + 1], s0, 64);
    const unsigned a2 = (unsigned)__shfl((int)pk0[2 * c], s1, 64);
    const unsigned b2 = (unsigned)__shfl((int)pk0[2 * c + 1], s1, 64);
    const unsigned a3 = (unsigned)__shfl((int)pk1[2 * c], s1, 64);
    const unsigned b3 = (unsigned)__shfl((int)pk1[2 * c + 1], s1, 64);
    union { short8v v; unsigned u[4]; } pb;
    pb.u[0] = hi ? b0 : a0;
    pb.u[1] = hi ? b1 : a1;
    pb.u[2] = hi ? b2 : a2;
    pb.u[3] = hi ? b3 : a3;
#pragma unroll
    for (int dt = 0; dt < 4; ++dt) {
      const int vr = dt * 16 + lq;
      const short8v va =
          *(const short8v*)(sVb + vr * 128 + (((c * 4 + g) ^ (vr & 7)) * 16));
      o[dt] = __builtin_amdgcn_mfma_f32_16x16x32_bf16(va, pb.v, o[dt], 0, 0, 0);
    }
  }
}

// ---------------------------------------------------------------------------
// Flash attention: block = (q-pair qp/{7-qp}, h, b). 4 waves x 16 q-rows,
// descending causal k-tiles shared by both q-tiles. Double-buffered
// global_load_lds staging. 1D grid with XCD-aware swizzle: the 4 qp-blocks
// of one (b,h) land on the same XCD so the 128KB K/V slab hits that L2.
// NO min-occupancy bound: R4's (256,4) capped regs at 128 -> ~300MB scratch
// spill traffic (WRITE_SIZE 16->158MB). Spill-free at lower occupancy wins.
// ---------------------------------------------------------------------------
__global__ __launch_bounds__(256) void attn_mfma(
    const ushort_t* __restrict__ Qf, const ushort_t* __restrict__ Kf,
    const ushort_t* __restrict__ Vt, const float4* __restrict__ QPn,
    const float4* __restrict__ KPn, ushort_t* __restrict__ O) {
  const int dsp = blockIdx.x;               // 0..1023
  const int w = (dsp & 7) * 128 + (dsp >> 3);  // XCD-contiguous work id
  const int qp = w & 3, h = (w >> 2) & 15, b = w >> 6;
  const int tid = threadIdx.x, lane = tid & 63, wid = tid >> 6;
  const int lq = lane & 15, g = lane >> 4;
  const bool pen = (h >= HALF);
  const float slope = -exp2f(-0.5f * (float)(h + 1));
  const size_t hoff = ((size_t)b * H + h) * S * DK;
  const ushort_t* Vslab = Vt + hoff;  // [dk][s] bf16
  const size_t bhh = (size_t)b * HALF + (h & (HALF - 1));

  __shared__ __align__(16) char sK[2][8192];
  __shared__ __align__(16) char sV[2][8192];
  __shared__ __align__(16) float4 sPen[2][64];

  const int qb_hi = 7 - qp, qb_lo = qp;
  const int qgH = qb_hi * 64 + wid * 16 + lq;
  const int qgL = qb_lo * 64 + wid * 16 + lq;

  short8v qfH[2], qfL[2];
  {
    const ushort_t* qr = Qf + hoff + (size_t)qgH * DK;
    qfH[0] = *(const short8v*)(qr + g * 8);
    qfH[1] = *(const short8v*)(qr + 32 + g * 8);
    qr = Qf + hoff + (size_t)qgL * DK;
    qfL[0] = *(const short8v*)(qr + g * 8);
    qfL[1] = *(const short8v*)(qr + 32 + g * 8);
    if (pen && g == 3) { qfH[1][7] = 0; qfL[1][7] = 0; }  // drop y from dot
  }
  float qnH = 0, qy2H = 0, xqyH = 0, qnL = 0, qy2L = 0, xqyL = 0;
  if (pen) {
    const float4 a = QPn[bhh * S + qgH];
    qnH = a.x; qy2H = a.y; xqyH = a.z;
    const float4 c = QPn[bhh * S + qgL];
    qnL = c.x; qy2L = c.y; xqyL = c.z;
  }

  const int r8 = lane >> 3;
  const int sl = ((lane & 7) ^ r8) * 8;  // pre-swizzled 16B-granule offset

  auto stage = [&](int buf, int kt) {
#pragma unroll
    for (int i = 0; i < 2; ++i) {
      const int row = wid * 16 + i * 8 + r8;
      gload16(Kf + hoff + (size_t)(kt * 64 + row) * DK + sl,
              &sK[buf][(wid * 2 + i) * 1024]);
      gload16(Vslab + (size_t)row * S + kt * 64 + sl,
              &sV[buf][(wid * 2 + i) * 1024]);
    }
    if (pen && wid == 0)
      gload16(&KPn[bhh * S + kt * 64 + lane], &sPen[buf][0]);
  };

  f32x4 oH[4], oL[4];
#pragma unroll
  for (int dt = 0; dt < 4; ++dt) {
    oH[dt] = (f32x4){0.f, 0.f, 0.f, 0.f};
    oL[dt] = (f32x4){0.f, 0.f, 0.f, 0.f};
  }
  float mH = -1e30f, lH = 0.f, mL = -1e30f, lL = 0.f;

  stage(0, qb_hi);
  __syncthreads();
  int cur = 0;
  for (int kt = qb_hi; kt >= 0; --kt) {
    if (kt > 0) stage(cur ^ 1, kt - 1);
    attn_tile(sK[cur], sV[cur], sPen[cur], qfH, qnH, qy2H, xqyH, pen, slope,
              qgH, kt * 64, lq, g, oH, mH, lH);
    if (kt <= qb_lo)
      attn_tile(sK[cur], sV[cur], sPen[cur], qfL, qnL, qy2L, xqyL, pen, slope,
                qgL, kt * 64, lq, g, oL, mL, lL);
    __syncthreads();  // drains vmcnt: next buffer complete, cur free to reuse
    cur ^= 1;
  }

  const float invH = 1.0f / lH;  // qgH >= 256, always nonzero
  const float invL = (qgL == 0) ? 0.f : 1.0f / lL;
  ushort_t* orH = O + ((size_t)b * S + qgH) * D + h * DK;
  ushort_t* orL = O + ((size_t)b * S + qgL) * D + h * DK;
#pragma unroll
  for (int dt = 0; dt < 4; ++dt) {
    uint2 u;
    u.x = cvtpk(oH[dt][0] * invH, oH[dt][1] * invH);
    u.y = cvtpk(oH[dt][2] * invH, oH[dt][3] * invH);
    *(uint2*)(orH + dt * 16 + g * 4) = u;
    uint2 v;
    v.x = cvtpk(oL[dt][0] * invL, oL[dt][1] * invL);
    v.y = cvtpk(oL[dt][2] * invL, oL[dt][3] * invL);
    *(uint2*)(orL + dt * 16 + g * 4) = v;
  }
}

// ---------------------------------------------------------------------------
extern "C" void kernel_launch(void* const* d_in, const int* in_sizes, int n_in,
                              void* d_out, int out_size, void* d_ws,
                              size_t ws_size, hipStream_t stream) {
  (void)in_sizes; (void)n_in; (void)out_size; (void)ws_size;
  const float* x  = (const float*)d_in[0];
  const float* Wq = (const float*)d_in[1];
  const float* bq = (const float*)d_in[2];
  const float* Wk = (const float*)d_in[3];
  const float* bk = (const float*)d_in[4];
  const float* Wv = (const float*)d_in[5];
  const float* bv = (const float*)d_in[6];
  const float* Wo = (const float*)d_in[7];
  const float* bo = (const float*)d_in[8];
  float* out = (float*)d_out;

  const size_t NQKV = (size_t)BS * H * S * DK;  // 8388608
  const size_t NW = (size_t)D * D;              // 1048576
  ushort_t* ws  = (ushort_t*)d_ws;
  ushort_t* Qb  = ws;
  ushort_t* Kbb = Qb + NQKV;
  ushort_t* Vtb = Kbb + NQKV;
  ushort_t* Ob  = Vtb + NQKV;
  ushort_t* xb  = Ob + NQKV;
  ushort_t* Wqb = xb + NQKV;
  ushort_t* Wkb = Wqb + NW;
  ushort_t* Wvb = Wkb + NW;
  ushort_t* Wob = Wvb + NW;
  float4* QPn = (float4*)(Wob + NW);
  float4* KPn = QPn + (size_t)BS * HALF * S;

  cvt_bf16<<<dim3(4096), 256, 0, stream>>>(x, xb, (int)(NQKV / 8));
  cvt_bf16<<<dim3(512), 256, 0, stream>>>(Wq, Wqb, (int)(NW / 8));
  cvt_bf16<<<dim3(512), 256, 0, stream>>>(Wk, Wkb, (int)(NW / 8));
  cvt_bf16<<<dim3(512), 256, 0, stream>>>(Wv, Wvb, (int)(NW / 8));
  cvt_bf16<<<dim3(512), 256, 0, stream>>>(Wo, Wob, (int)(NW / 8));

  dim3 gg(8, 64);
  gemm_mfma<0><<<gg, 256, 0, stream>>>(xb, Wqb, bq, Qb);
  gemm_mfma<0><<<gg, 256, 0, stream>>>(xb, Wkb, bk, Kbb);
  gemm_mfma<1><<<gg, 256, 0, stream>>>(xb, Wvb, bv, Vtb);
  psi_kernel<<<dim3(S / 4, HALF, BS), 256, 0, stream>>>(Qb, QPn);
  psi_kernel<<<dim3(S / 4, HALF, BS), 256, 0, stream>>>(Kbb, KPn);
  attn_mfma<<<dim3(1024), 256, 0, stream>>>(Qb, Kbb, Vtb, QPn, KPn, Ob);
  gemm_mfma<2><<<gg, 256, 0, stream>>>(Ob, Wob, bo, out);
}